// Round 2
// baseline (4863.605 us; speedup 1.0000x reference)
//
#include <hip/hip_runtime.h>
#include <hip/hip_bf16.h>

// SparseBottleneck, output-stationary rewrite:
//   CSR-invert (out_tile,k) -> packed records; per-tile LDS fp32 accumulator;
//   no global atomics. conv2 fused into conv1 epilogue; mask fused into conv3.

typedef __attribute__((ext_vector_type(8))) short short8;
typedef __attribute__((ext_vector_type(4))) float f32x4;

#define CDIM 128
#define TROWS 64
#define KTAPS 27
#define NEG_SLOPE 0.2f

__device__ __forceinline__ unsigned short f2bf(float x) {
    union { float f; unsigned u; } un; un.f = x;
    unsigned r = un.u + 0x7fffu + ((un.u >> 16) & 1u);   // RNE
    return (unsigned short)(r >> 16);
}

__device__ __forceinline__ float lrelu(float x) {
    return x >= 0.f ? x : NEG_SLOPE * x;
}

// swizzled LDS index (ushort elements): 128 cols row-major, 8-elem chunk XOR (r&15)
__device__ __forceinline__ int swz(int r, int c) {
    return (r << 7) + ((((c >> 3) ^ (r & 15)) << 3));
}

// ---------------------------------------------------------------- converters
__global__ void cvt_feats_kernel(const float* __restrict__ in,
                                 unsigned short* __restrict__ out, int n4) {
    int i = blockIdx.x * blockDim.x + threadIdx.x;
    if (i >= n4) return;
    float4 v = reinterpret_cast<const float4*>(in)[i];
    ushort4 o;
    o.x = f2bf(v.x); o.y = f2bf(v.y); o.z = f2bf(v.z); o.w = f2bf(v.w);
    reinterpret_cast<ushort4*>(out)[i] = o;
}

__global__ void cvt_weights_kernel(const float* __restrict__ W1,
                                   const float* __restrict__ W2,
                                   const float* __restrict__ W3,
                                   unsigned short* __restrict__ W1t,
                                   unsigned short* __restrict__ W2t,
                                   unsigned short* __restrict__ W3t) {
    const int KW = KTAPS * CDIM * CDIM;
    int t = blockIdx.x * blockDim.x + threadIdx.x;
    if (t < KW) {
        int k = t >> 14, r = t & 16383, n = r >> 7, kk = r & 127;
        W1t[t] = f2bf(W1[(k << 14) + (kk << 7) + n]);
    } else if (t < 2 * KW) {
        int t2 = t - KW;
        int k = t2 >> 14, r = t2 & 16383, n = r >> 7, kk = r & 127;
        W3t[t2] = f2bf(W3[(k << 14) + (kk << 7) + n]);
    } else if (t < 2 * KW + CDIM * CDIM) {
        int t2 = t - 2 * KW;
        int n = t2 >> 7, kk = t2 & 127;
        W2t[t2] = f2bf(W2[(kk << 7) + n]);
    }
}

// ---------------------------------------------------------------- CSR build
__global__ void hist_kernel(const int* __restrict__ om, int* __restrict__ bins, int M) {
    int m = blockIdx.x * 256 + threadIdx.x;
    int k = blockIdx.y;
    if (m >= M) return;
    int o = om[(size_t)k * M + m];
    atomicAdd(&bins[(o >> 6) * KTAPS + k], 1);
}

__global__ void scan_kernel(const int* __restrict__ bins, int* __restrict__ starts, int B) {
    __shared__ int lds[1024];
    int t = threadIdx.x;
    int seg = (B + 1023) >> 10;
    int base = t * seg;
    int s = 0;
    for (int i = 0; i < seg; ++i) { int idx = base + i; if (idx < B) s += bins[idx]; }
    lds[t] = s;
    __syncthreads();
    for (int off = 1; off < 1024; off <<= 1) {
        int v = lds[t];
        int add = (t >= off) ? lds[t - off] : 0;
        __syncthreads();
        lds[t] = v + add;
        __syncthreads();
    }
    int run = (t == 0) ? 0 : lds[t - 1];
    for (int i = 0; i < seg; ++i) {
        int idx = base + i;
        if (idx < B) { starts[idx] = run; run += bins[idx]; }
    }
    if (t == 1023) starts[B] = lds[1023];
}

__global__ void scatter_kernel(const int* __restrict__ im, const int* __restrict__ om,
                               const int* __restrict__ starts, int* __restrict__ cursor,
                               unsigned* __restrict__ rec, int M) {
    int m = blockIdx.x * 256 + threadIdx.x;
    int k = blockIdx.y;
    if (m >= M) return;
    size_t e = (size_t)k * M + m;
    int o = om[e];
    int bin = (o >> 6) * KTAPS + k;
    int pos = starts[bin] + atomicAdd(&cursor[bin], 1);
    rec[pos] = ((unsigned)im[e] << 6) | (unsigned)(o & 63);
}

// ---------------------------------------------------------------- inverted sparse conv
// One block owns 64 output rows. Loop k: stage W_k, gather contributor rows (CSR),
// MFMA, ds_add_f32 into LDS accumulator. Epilogue mode1: fused conv2 (lrelu->bf16
// ->@W2->lrelu->c2 bf16). mode2: *mask, fp32 out.
__global__ __launch_bounds__(256, 2)
void sconv_inv_kernel(const unsigned short* __restrict__ A,    // [N,128] bf16
                      const unsigned short* __restrict__ Wt,   // [27][128][128] bf16 [k][n][kk]
                      const unsigned* __restrict__ rec,
                      const int* __restrict__ starts,
                      const unsigned short* __restrict__ W2t,  // mode1 only
                      unsigned short* __restrict__ c2,         // mode1 out
                      const float* __restrict__ mask,          // mode2 only
                      float* __restrict__ outp,                // mode2 out
                      int mode) {
    __shared__ float          accW[TROWS * CDIM];   // 32 KB
    __shared__ unsigned short lA[TROWS * CDIM];     // 16 KB
    __shared__ unsigned short lW[CDIM * CDIM];      // 32 KB  (sum = 80 KB -> 2 blk/CU)

    const int t    = blockIdx.x;
    const int tid  = threadIdx.x;
    const int w    = tid >> 6;
    const int lane = tid & 63;
    const int lrow = lane & 15;
    const int quad = lane >> 4;

    #pragma unroll
    for (int i = 0; i < 8; ++i)
        reinterpret_cast<float4*>(accW)[i * 256 + tid] = make_float4(0.f, 0.f, 0.f, 0.f);

    for (int k = 0; k < KTAPS; ++k) {
        __syncthreads();   // protect lW (and lA) from previous iteration's readers
        const unsigned short* wk = Wt + (size_t)k * (CDIM * CDIM);
        #pragma unroll
        for (int i = 0; i < 8; ++i) {
            int flat = (i * 256 + tid) * 8;
            int row = flat >> 7, col = flat & 127;
            *reinterpret_cast<short8*>(&lW[swz(row, col)]) =
                *reinterpret_cast<const short8*>(wk + flat);
        }
        const int bin = t * KTAPS + k;
        const int s0  = starts[bin];
        const int cnt = starts[bin + 1] - s0;

        for (int base = 0; base < cnt; base += TROWS) {
            int c = cnt - base; if (c > TROWS) c = TROWS;
            if (base > 0) __syncthreads();          // protect lA from prev chunk's readers
            #pragma unroll
            for (int p = 0; p < 4; ++p) {
                int r = p * 16 + (tid >> 4);
                if (r < c) {
                    unsigned rv = rec[s0 + base + r];
                    int src = (int)(rv >> 6);
                    *reinterpret_cast<short8*>(&lA[swz(r, (tid & 15) * 8)]) =
                        *reinterpret_cast<const short8*>(A + (size_t)src * CDIM + (tid & 15) * 8);
                }
            }
            __syncthreads();
            int r16 = (c + 15) >> 4;
            short8 b0[4], b1[4];
            #pragma unroll
            for (int kf = 0; kf < 4; ++kf) {
                b0[kf] = *reinterpret_cast<const short8*>(&lW[swz(w * 32 + lrow,      kf * 32 + quad * 8)]);
                b1[kf] = *reinterpret_cast<const short8*>(&lW[swz(w * 32 + 16 + lrow, kf * 32 + quad * 8)]);
            }
            for (int rt = 0; rt < r16; ++rt) {
                f32x4 acc0 = {0.f, 0.f, 0.f, 0.f}, acc1 = {0.f, 0.f, 0.f, 0.f};
                #pragma unroll
                for (int kf = 0; kf < 4; ++kf) {
                    short8 av = *reinterpret_cast<const short8*>(&lA[swz(rt * 16 + lrow, kf * 32 + quad * 8)]);
                    acc0 = __builtin_amdgcn_mfma_f32_16x16x32_bf16(av, b0[kf], acc0, 0, 0, 0);
                    acc1 = __builtin_amdgcn_mfma_f32_16x16x32_bf16(av, b1[kf], acc1, 0, 0, 0);
                }
                #pragma unroll
                for (int reg = 0; reg < 4; ++reg) {
                    int rr = rt * 16 + quad * 4 + reg;
                    if (rr < c) {
                        int slot = (int)(rec[s0 + base + rr] & 63u);
                        atomicAdd(&accW[slot * CDIM + w * 32 + lrow],      acc0[reg]);
                        atomicAdd(&accW[slot * CDIM + w * 32 + 16 + lrow], acc1[reg]);
                    }
                }
            }
        }
    }
    __syncthreads();   // all ds_add done; lW/lA free

    if (mode == 1) {
        // stage W2
        #pragma unroll
        for (int i = 0; i < 8; ++i) {
            int flat = (i * 256 + tid) * 8;
            int row = flat >> 7, col = flat & 127;
            *reinterpret_cast<short8*>(&lW[swz(row, col)]) =
                *reinterpret_cast<const short8*>(W2t + flat);
        }
        // accW --lrelu,bf16--> lA
        {
            int row = tid >> 2, c0 = (tid & 3) * 32;
            #pragma unroll
            for (int j = 0; j < 4; ++j) {
                const float4* sp = reinterpret_cast<const float4*>(accW + row * CDIM + c0 + j * 8);
                float4 x0 = sp[0], x1 = sp[1];
                short8 v;
                v[0] = (short)f2bf(lrelu(x0.x)); v[1] = (short)f2bf(lrelu(x0.y));
                v[2] = (short)f2bf(lrelu(x0.z)); v[3] = (short)f2bf(lrelu(x0.w));
                v[4] = (short)f2bf(lrelu(x1.x)); v[5] = (short)f2bf(lrelu(x1.y));
                v[6] = (short)f2bf(lrelu(x1.z)); v[7] = (short)f2bf(lrelu(x1.w));
                *reinterpret_cast<short8*>(&lA[swz(row, c0 + j * 8)]) = v;
            }
        }
        __syncthreads();
        unsigned short* cacc = reinterpret_cast<unsigned short*>(accW);
        #pragma unroll
        for (int rt = 0; rt < 4; ++rt) {
            f32x4 acc0 = {0.f, 0.f, 0.f, 0.f}, acc1 = {0.f, 0.f, 0.f, 0.f};
            #pragma unroll
            for (int kf = 0; kf < 4; ++kf) {
                short8 av = *reinterpret_cast<const short8*>(&lA[swz(rt * 16 + lrow, kf * 32 + quad * 8)]);
                short8 b0 = *reinterpret_cast<const short8*>(&lW[swz(w * 32 + lrow,      kf * 32 + quad * 8)]);
                short8 b1 = *reinterpret_cast<const short8*>(&lW[swz(w * 32 + 16 + lrow, kf * 32 + quad * 8)]);
                acc0 = __builtin_amdgcn_mfma_f32_16x16x32_bf16(av, b0, acc0, 0, 0, 0);
                acc1 = __builtin_amdgcn_mfma_f32_16x16x32_bf16(av, b1, acc1, 0, 0, 0);
            }
            #pragma unroll
            for (int reg = 0; reg < 4; ++reg) {
                int rr = rt * 16 + quad * 4 + reg;
                cacc[rr * CDIM + w * 32 + lrow]      = f2bf(lrelu(acc0[reg]));
                cacc[rr * CDIM + w * 32 + 16 + lrow] = f2bf(lrelu(acc1[reg]));
            }
        }
        __syncthreads();
        #pragma unroll
        for (int i = 0; i < 4; ++i) {
            int flat = (i * 256 + tid) * 8;
            *reinterpret_cast<short8*>(c2 + (size_t)t * TROWS * CDIM + flat) =
                *reinterpret_cast<const short8*>(cacc + flat);
        }
    } else {
        int row = tid >> 2, c0 = (tid & 3) * 32;
        float mval = mask[t * TROWS + row];
        const float4* sp = reinterpret_cast<const float4*>(accW + row * CDIM + c0);
        float4* dp = reinterpret_cast<float4*>(outp + (size_t)t * TROWS * CDIM + row * CDIM + c0);
        #pragma unroll
        for (int j = 0; j < 8; ++j) {
            float4 v = sp[j];
            v.x *= mval; v.y *= mval; v.z *= mval; v.w *= mval;
            dp[j] = v;
        }
    }
}

// ---------------------------------------------------------------- launch
extern "C" void kernel_launch(void* const* d_in, const int* in_sizes, int n_in,
                              void* d_out, int out_size, void* d_ws, size_t ws_size,
                              hipStream_t stream) {
    const float* feats   = (const float*)d_in[0];
    const float* W1      = (const float*)d_in[1];
    const float* W2      = (const float*)d_in[2];
    const float* W3      = (const float*)d_in[3];
    const int*   in_map  = (const int*)d_in[4];
    const int*   out_map = (const int*)d_in[5];
    const float* mask    = (const float*)d_in[6];
    float*       out     = (float*)d_out;

    const int N  = in_sizes[0] / CDIM;       // 200000
    const int M  = in_sizes[4] / KTAPS;      // 100000
    const int NT = (N + TROWS - 1) / TROWS;  // 3125
    const int B  = NT * KTAPS;               // 84375
    const size_t E = (size_t)KTAPS * M;

    char* p = (char*)d_ws;
    auto take = [&](size_t bytes) { char* r = p; p += (bytes + 15) & ~(size_t)15; return r; };
    unsigned short* feats_bf = (unsigned short*)take((size_t)N * CDIM * 2);
    unsigned short* c2_bf    = (unsigned short*)take((size_t)N * CDIM * 2);
    unsigned short* W1t      = (unsigned short*)take((size_t)KTAPS * CDIM * CDIM * 2);
    unsigned short* W3t      = (unsigned short*)take((size_t)KTAPS * CDIM * CDIM * 2);
    unsigned short* W2t      = (unsigned short*)take((size_t)CDIM * CDIM * 2);
    int*            bins     = (int*)take((size_t)(B + 1) * 4);
    int*            starts   = (int*)take((size_t)(B + 1) * 4);
    unsigned*       rec      = (unsigned*)take(E * 4);
    if ((size_t)(p - (char*)d_ws) > ws_size) return;   // loud fail

    const int n4 = N * CDIM / 4;
    cvt_feats_kernel<<<(n4 + 255) / 256, 256, 0, stream>>>(feats, feats_bf, n4);
    const int wtot = 2 * KTAPS * CDIM * CDIM + CDIM * CDIM;
    cvt_weights_kernel<<<(wtot + 255) / 256, 256, 0, stream>>>(W1, W2, W3, W1t, W2t, W3t);

    hipMemsetAsync(bins, 0, (size_t)(B + 1) * 4, stream);
    dim3 gm((M + 255) / 256, KTAPS);
    hist_kernel<<<gm, 256, 0, stream>>>(out_map, bins, M);
    scan_kernel<<<1, 1024, 0, stream>>>(bins, starts, B);
    hipMemsetAsync(bins, 0, (size_t)(B + 1) * 4, stream);
    scatter_kernel<<<gm, 256, 0, stream>>>(in_map, out_map, starts, bins, rec, M);

    sconv_inv_kernel<<<NT, 256, 0, stream>>>(feats_bf, W1t, rec, starts,
                                             W2t, c2_bf, nullptr, nullptr, 1);
    sconv_inv_kernel<<<NT, 256, 0, stream>>>(c2_bf, W3t, rec, starts,
                                             nullptr, nullptr, mask, out, 2);
}

// Round 3
// 3269.070 us; speedup vs baseline: 1.4878x; 1.4878x over previous
//
#include <hip/hip_runtime.h>
#include <hip/hip_bf16.h>

// SparseBottleneck v3: materialize per-contribution products Y (bf16, perm cols),
// then segmented reduce per output row (one wave/row, no atomics in hot path).
// Tiered on ws_size: tap-groups of g (g=27 => single pass); atomic fallback if tiny ws.

typedef __attribute__((ext_vector_type(8))) short short8;
typedef __attribute__((ext_vector_type(4))) float f32x4;

#define CDIM 128
#define KTAPS 27
#define NEG_SLOPE 0.2f

__device__ __forceinline__ unsigned short f2bf(float x) {
    union { float f; unsigned u; } un; un.f = x;
    unsigned r = un.u + 0x7fffu + ((un.u >> 16) & 1u);   // RNE
    return (unsigned short)(r >> 16);
}
__device__ __forceinline__ float bflo(unsigned v) { union { unsigned u; float f; } un; un.u = v << 16; return un.f; }
__device__ __forceinline__ float bfhi(unsigned v) { union { unsigned u; float f; } un; un.u = v & 0xffff0000u; return un.f; }
__device__ __forceinline__ float lrelu(float x) { return x >= 0.f ? x : NEG_SLOPE * x; }
// swizzled LDS index (ushort elems): breaks 8-way bank conflicts on fragment reads
__device__ __forceinline__ int swz(int r, int c) { return (r << 7) + ((((c >> 3) ^ (r & 15)) << 3)); }
// storage position q -> true column: q = wc + lrow*4 + j  <->  col = wc + j*16 + lrow
__device__ __forceinline__ int pcol(int q) { return (q & 64) | ((q & 3) << 4) | ((q >> 2) & 15); }

// ---------------------------------------------------------------- converters
__global__ void cvt_feats_kernel(const float* __restrict__ in,
                                 unsigned short* __restrict__ out, int n4) {
    int i = blockIdx.x * blockDim.x + threadIdx.x;
    if (i >= n4) return;
    float4 v = reinterpret_cast<const float4*>(in)[i];
    ushort4 o;
    o.x = f2bf(v.x); o.y = f2bf(v.y); o.z = f2bf(v.z); o.w = f2bf(v.w);
    reinterpret_cast<ushort4*>(out)[i] = o;
}

// W1t true (A=feats true layout); W2t/W3t rows permuted by pcol when perm=1
// (A=c1/c2 stored in perm order). Layout: Wt[k][n][kk].
__global__ void cvt_weights_kernel(const float* __restrict__ W1,
                                   const float* __restrict__ W2,
                                   const float* __restrict__ W3,
                                   unsigned short* __restrict__ W1t,
                                   unsigned short* __restrict__ W2t,
                                   unsigned short* __restrict__ W3t, int perm) {
    const int KW = KTAPS * CDIM * CDIM;
    int t = blockIdx.x * blockDim.x + threadIdx.x;
    if (t < KW) {
        int k = t >> 14, r = t & 16383, n = r >> 7, kk = r & 127;
        W1t[t] = f2bf(W1[(k << 14) + (kk << 7) + n]);
    } else if (t < 2 * KW) {
        int t2 = t - KW;
        int k = t2 >> 14, r = t2 & 16383, n = r >> 7, q = r & 127;
        int kk = perm ? pcol(q) : q;
        W3t[t2] = f2bf(W3[(k << 14) + (kk << 7) + n]);
    } else if (t < 2 * KW + CDIM * CDIM) {
        int t2 = t - 2 * KW;
        int n = t2 >> 7, q = t2 & 127;
        int kk = perm ? pcol(q) : q;
        W2t[t2] = f2bf(W2[(kk << 7) + n]);
    }
}

// ---------------------------------------------------------------- CSR build (bin = out_row*ng + k/g)
__global__ void hist_kernel(const int* __restrict__ om, int* __restrict__ bins,
                            int M, int ng, int g) {
    int m = blockIdx.x * 256 + threadIdx.x;
    int k = blockIdx.y;
    if (m >= M) return;
    int o = om[(size_t)k * M + m];
    atomicAdd(&bins[o * ng + k / g], 1);
}

__global__ void scan_kernel(const int* __restrict__ bins, int* __restrict__ starts, int B) {
    __shared__ int lds[1024];
    int t = threadIdx.x;
    int seg = (B + 1023) >> 10;
    int base = t * seg;
    int s = 0;
    for (int i = 0; i < seg; ++i) { int idx = base + i; if (idx < B) s += bins[idx]; }
    lds[t] = s;
    __syncthreads();
    for (int off = 1; off < 1024; off <<= 1) {
        int v = lds[t];
        int add = (t >= off) ? lds[t - off] : 0;
        __syncthreads();
        lds[t] = v + add;
        __syncthreads();
    }
    int run = (t == 0) ? 0 : lds[t - 1];
    for (int i = 0; i < seg; ++i) {
        int idx = base + i;
        if (idx < B) { starts[idx] = run; run += bins[idx]; }
    }
    if (t == 1023) starts[B] = lds[1023];
}

__global__ void scatter_kernel(const int* __restrict__ om,
                               const int* __restrict__ starts, int* __restrict__ cursor,
                               unsigned* __restrict__ rec, int M, int ng, int g) {
    int m = blockIdx.x * 256 + threadIdx.x;
    int k = blockIdx.y;
    if (m >= M) return;
    int o = om[(size_t)k * M + m];
    int bin = o * ng + k / g;
    int pos = starts[bin] + atomicAdd(&cursor[bin], 1);
    rec[pos] = (unsigned)(k * M + m);          // e_global
}

// ---------------------------------------------------------------- phase 1: gather-GEMM -> Y (bf16, perm cols)
__global__ __launch_bounds__(256, 2)
void gemm_gather_kernel(const unsigned short* __restrict__ A,    // [N,128] bf16
                        const unsigned short* __restrict__ Wt,   // [27][128][128] [k][n][kk]
                        const int* __restrict__ in_map,          // [K,M]
                        unsigned short* __restrict__ Y,          // [(kh-klo)*M, 128] perm
                        int M, int klo) {
    const int k     = klo + blockIdx.y;
    const int mbase = blockIdx.x * 128;
    const int tid   = threadIdx.x;

    __shared__ unsigned short lA[128 * CDIM];   // 32 KB
    __shared__ unsigned short lW[CDIM * CDIM];  // 32 KB

    const unsigned short* wk = Wt + (size_t)k * 16384;
    #pragma unroll
    for (int i = 0; i < 8; ++i) {
        int flat = (i * 256 + tid) * 8;
        int row = flat >> 7, col = flat & 127;
        *reinterpret_cast<short8*>(&lW[swz(row, col)]) =
            *reinterpret_cast<const short8*>(wk + flat);
    }
    const int* imk = in_map + (size_t)k * M;
    #pragma unroll
    for (int p = 0; p < 8; ++p) {
        int r = p * 16 + (tid >> 4);
        int c = (tid & 15) * 8;
        int m = mbase + r;
        short8 v = {0, 0, 0, 0, 0, 0, 0, 0};
        if (m < M) {
            int arow = __ldg(imk + m);
            v = *reinterpret_cast<const short8*>(A + (size_t)arow * CDIM + c);
        }
        *reinterpret_cast<short8*>(&lA[swz(r, c)]) = v;
    }
    __syncthreads();

    const int wid = tid >> 6, lane = tid & 63;
    const int wr = (wid >> 1) * 64, wc = (wid & 1) * 64;
    const int lrow = lane & 15, quad = lane >> 4;

    f32x4 acc[4][4];
    #pragma unroll
    for (int i = 0; i < 4; ++i)
        #pragma unroll
        for (int j = 0; j < 4; ++j)
            acc[i][j] = {0.f, 0.f, 0.f, 0.f};

    #pragma unroll
    for (int s = 0; s < 4; ++s) {
        const int kf = s * 32 + quad * 8;
        short8 a[4], b[4];
        #pragma unroll
        for (int i = 0; i < 4; ++i)
            a[i] = *reinterpret_cast<const short8*>(&lA[swz(wr + i * 16 + lrow, kf)]);
        #pragma unroll
        for (int j = 0; j < 4; ++j)
            b[j] = *reinterpret_cast<const short8*>(&lW[swz(wc + j * 16 + lrow, kf)]);
        #pragma unroll
        for (int i = 0; i < 4; ++i)
            #pragma unroll
            for (int j = 0; j < 4; ++j)
                acc[i][j] = __builtin_amdgcn_mfma_f32_16x16x32_bf16(a[i], b[j], acc[i][j], 0, 0, 0);
    }

    // epilogue: perm-order 8B stores (pos q = wc + lrow*4 + j holds col wc + j*16 + lrow)
    const size_t ybase = (size_t)(k - klo) * M;
    #pragma unroll
    for (int i = 0; i < 4; ++i) {
        #pragma unroll
        for (int reg = 0; reg < 4; ++reg) {
            int m = mbase + wr + i * 16 + quad * 4 + reg;
            if (m < M) {
                ushort4 pk;
                pk.x = f2bf(acc[i][0][reg]);
                pk.y = f2bf(acc[i][1][reg]);
                pk.z = f2bf(acc[i][2][reg]);
                pk.w = f2bf(acc[i][3][reg]);
                *reinterpret_cast<ushort4*>(Y + (ybase + m) * CDIM + wc + lrow * 4) = pk;
            }
        }
    }
}

// ---------------------------------------------------------------- phase 2: segmented reduce (1 wave / out row)
__global__ void reduce_kernel(const unsigned short* __restrict__ Y,
                              const unsigned* __restrict__ rec,
                              const int* __restrict__ starts,
                              float* __restrict__ acc,            // [N,128] fp32 (d_out)
                              const float* __restrict__ mask,
                              int N, int ng, int grp, unsigned eoff,
                              int first, int final_mask) {
    int row = blockIdx.x * 4 + (threadIdx.x >> 6);
    if (row >= N) return;
    int lane = threadIdx.x & 63;
    int bin = row * ng + grp;
    int s0 = starts[bin], cnt = starts[bin + 1] - s0;
    float a0 = 0.f, a1 = 0.f;
    if (!first) {
        float2 p = *reinterpret_cast<const float2*>(acc + (size_t)row * CDIM + 2 * lane);
        a0 = p.x; a1 = p.y;
    }
    const unsigned* rp = rec + s0;
    int c = 0;
    for (; c + 4 <= cnt; c += 4) {
        unsigned e0 = rp[c] - eoff, e1 = rp[c + 1] - eoff;
        unsigned e2 = rp[c + 2] - eoff, e3 = rp[c + 3] - eoff;
        unsigned v0 = *reinterpret_cast<const unsigned*>(Y + (size_t)e0 * CDIM + 2 * lane);
        unsigned v1 = *reinterpret_cast<const unsigned*>(Y + (size_t)e1 * CDIM + 2 * lane);
        unsigned v2 = *reinterpret_cast<const unsigned*>(Y + (size_t)e2 * CDIM + 2 * lane);
        unsigned v3 = *reinterpret_cast<const unsigned*>(Y + (size_t)e3 * CDIM + 2 * lane);
        a0 += (bflo(v0) + bflo(v1)) + (bflo(v2) + bflo(v3));
        a1 += (bfhi(v0) + bfhi(v1)) + (bfhi(v2) + bfhi(v3));
    }
    for (; c < cnt; ++c) {
        unsigned e = rp[c] - eoff;
        unsigned v = *reinterpret_cast<const unsigned*>(Y + (size_t)e * CDIM + 2 * lane);
        a0 += bflo(v); a1 += bfhi(v);
    }
    if (!final_mask) {
        // keep perm order (coalesced 8B); consumers compensate via permuted W rows
        *reinterpret_cast<float2*>(acc + (size_t)row * CDIM + 2 * lane) = make_float2(a0, a1);
    } else {
        // un-permute + mask on final store (whole row owned by this wave: loads precede stores)
        float mv = mask[row];
        acc[(size_t)row * CDIM + pcol(2 * lane)]     = a0 * mv;
        acc[(size_t)row * CDIM + pcol(2 * lane + 1)] = a1 * mv;
    }
}

// ---------------------------------------------------------------- conv2 (dense, perm in/out)
__global__ __launch_bounds__(256, 2)
void conv2_perm_kernel(const float* __restrict__ c1,              // [N,128] fp32 perm, pre-lrelu
                       const unsigned short* __restrict__ W2t,    // perm rows
                       unsigned short* __restrict__ c2,           // [N,128] bf16 perm
                       int N) {
    const int mbase = blockIdx.x * 128;
    const int tid   = threadIdx.x;

    __shared__ unsigned short lA[128 * CDIM];
    __shared__ unsigned short lW[CDIM * CDIM];

    #pragma unroll
    for (int i = 0; i < 8; ++i) {
        int flat = (i * 256 + tid) * 8;
        int row = flat >> 7, col = flat & 127;
        *reinterpret_cast<short8*>(&lW[swz(row, col)]) =
            *reinterpret_cast<const short8*>(W2t + flat);
    }
    #pragma unroll
    for (int p = 0; p < 8; ++p) {
        int r = p * 16 + (tid >> 4);
        int c = (tid & 15) * 8;
        int m = mbase + r;
        short8 v = {0, 0, 0, 0, 0, 0, 0, 0};
        if (m < N) {
            const float4* src = reinterpret_cast<const float4*>(c1 + (size_t)m * CDIM + c);
            float4 x0 = src[0], x1 = src[1];
            v[0] = (short)f2bf(lrelu(x0.x)); v[1] = (short)f2bf(lrelu(x0.y));
            v[2] = (short)f2bf(lrelu(x0.z)); v[3] = (short)f2bf(lrelu(x0.w));
            v[4] = (short)f2bf(lrelu(x1.x)); v[5] = (short)f2bf(lrelu(x1.y));
            v[6] = (short)f2bf(lrelu(x1.z)); v[7] = (short)f2bf(lrelu(x1.w));
        }
        *reinterpret_cast<short8*>(&lA[swz(r, c)]) = v;
    }
    __syncthreads();

    const int wid = tid >> 6, lane = tid & 63;
    const int wr = (wid >> 1) * 64, wc = (wid & 1) * 64;
    const int lrow = lane & 15, quad = lane >> 4;

    f32x4 acc[4][4];
    #pragma unroll
    for (int i = 0; i < 4; ++i)
        #pragma unroll
        for (int j = 0; j < 4; ++j)
            acc[i][j] = {0.f, 0.f, 0.f, 0.f};

    #pragma unroll
    for (int s = 0; s < 4; ++s) {
        const int kf = s * 32 + quad * 8;
        short8 a[4], b[4];
        #pragma unroll
        for (int i = 0; i < 4; ++i)
            a[i] = *reinterpret_cast<const short8*>(&lA[swz(wr + i * 16 + lrow, kf)]);
        #pragma unroll
        for (int j = 0; j < 4; ++j)
            b[j] = *reinterpret_cast<const short8*>(&lW[swz(wc + j * 16 + lrow, kf)]);
        #pragma unroll
        for (int i = 0; i < 4; ++i)
            #pragma unroll
            for (int j = 0; j < 4; ++j)
                acc[i][j] = __builtin_amdgcn_mfma_f32_16x16x32_bf16(a[i], b[j], acc[i][j], 0, 0, 0);
    }

    #pragma unroll
    for (int i = 0; i < 4; ++i) {
        #pragma unroll
        for (int reg = 0; reg < 4; ++reg) {
            int m = mbase + wr + i * 16 + quad * 4 + reg;
            if (m < N) {
                ushort4 pk;
                pk.x = f2bf(lrelu(acc[i][0][reg]));
                pk.y = f2bf(lrelu(acc[i][1][reg]));
                pk.z = f2bf(lrelu(acc[i][2][reg]));
                pk.w = f2bf(lrelu(acc[i][3][reg]));
                *reinterpret_cast<ushort4*>(c2 + (size_t)m * CDIM + wc + lrow * 4) = pk;
            }
        }
    }
}

// ---------------------------------------------------------------- atomic fallback path (round-1, known-good)
__global__ __launch_bounds__(256, 2)
void sconv_atomic_kernel(const unsigned short* __restrict__ A,
                         const unsigned short* __restrict__ Wt,
                         const int* __restrict__ in_map,
                         const int* __restrict__ out_map,
                         float* __restrict__ out, int M) {
    const int k     = blockIdx.y;
    const int mbase = blockIdx.x * 128;
    const int tid   = threadIdx.x;

    __shared__ unsigned short lA[128 * CDIM];
    __shared__ unsigned short lW[CDIM * CDIM];

    const unsigned short* wk = Wt + (size_t)k * 16384;
    #pragma unroll
    for (int i = 0; i < 8; ++i) {
        int flat = (i * 256 + tid) * 8;
        int row = flat >> 7, col = flat & 127;
        *reinterpret_cast<short8*>(&lW[swz(row, col)]) =
            *reinterpret_cast<const short8*>(wk + flat);
    }
    const int* imk = in_map + (size_t)k * M;
    #pragma unroll
    for (int p = 0; p < 8; ++p) {
        int r = p * 16 + (tid >> 4);
        int c = (tid & 15) * 8;
        int m = mbase + r;
        short8 v = {0, 0, 0, 0, 0, 0, 0, 0};
        if (m < M) {
            int arow = __ldg(imk + m);
            v = *reinterpret_cast<const short8*>(A + (size_t)arow * CDIM + c);
        }
        *reinterpret_cast<short8*>(&lA[swz(r, c)]) = v;
    }
    __syncthreads();

    const int wid = tid >> 6, lane = tid & 63;
    const int wr = (wid >> 1) * 64, wc = (wid & 1) * 64;
    const int lrow = lane & 15, quad = lane >> 4;

    f32x4 acc[4][4];
    #pragma unroll
    for (int i = 0; i < 4; ++i)
        #pragma unroll
        for (int j = 0; j < 4; ++j)
            acc[i][j] = {0.f, 0.f, 0.f, 0.f};

    #pragma unroll
    for (int s = 0; s < 4; ++s) {
        const int kf = s * 32 + quad * 8;
        short8 a[4], b[4];
        #pragma unroll
        for (int i = 0; i < 4; ++i)
            a[i] = *reinterpret_cast<const short8*>(&lA[swz(wr + i * 16 + lrow, kf)]);
        #pragma unroll
        for (int j = 0; j < 4; ++j)
            b[j] = *reinterpret_cast<const short8*>(&lW[swz(wc + j * 16 + lrow, kf)]);
        #pragma unroll
        for (int i = 0; i < 4; ++i)
            #pragma unroll
            for (int j = 0; j < 4; ++j)
                acc[i][j] = __builtin_amdgcn_mfma_f32_16x16x32_bf16(a[i], b[j], acc[i][j], 0, 0, 0);
    }

    const int* omk = out_map + (size_t)k * M;
    #pragma unroll
    for (int i = 0; i < 4; ++i) {
        #pragma unroll
        for (int reg = 0; reg < 4; ++reg) {
            int m = mbase + wr + i * 16 + quad * 4 + reg;
            if (m < M) {
                int orow = __ldg(omk + m);
                float* dst = out + (size_t)orow * CDIM + wc + lrow;
                #pragma unroll
                for (int j = 0; j < 4; ++j)
                    unsafeAtomicAdd(dst + j * 16, acc[i][j][reg]);
            }
        }
    }
}

__global__ __launch_bounds__(256, 2)
void conv2_true_kernel(const float* __restrict__ c1,
                       const unsigned short* __restrict__ W2t,
                       unsigned short* __restrict__ c2, int N) {
    const int mbase = blockIdx.x * 128;
    const int tid   = threadIdx.x;

    __shared__ unsigned short lA[128 * CDIM];
    __shared__ unsigned short lW[CDIM * CDIM];

    #pragma unroll
    for (int i = 0; i < 8; ++i) {
        int flat = (i * 256 + tid) * 8;
        int row = flat >> 7, col = flat & 127;
        *reinterpret_cast<short8*>(&lW[swz(row, col)]) =
            *reinterpret_cast<const short8*>(W2t + flat);
    }
    #pragma unroll
    for (int p = 0; p < 8; ++p) {
        int r = p * 16 + (tid >> 4);
        int c = (tid & 15) * 8;
        int m = mbase + r;
        short8 v = {0, 0, 0, 0, 0, 0, 0, 0};
        if (m < N) {
            const float4* src = reinterpret_cast<const float4*>(c1 + (size_t)m * CDIM + c);
            float4 x0 = src[0], x1 = src[1];
            v[0] = (short)f2bf(lrelu(x0.x)); v[1] = (short)f2bf(lrelu(x0.y));
            v[2] = (short)f2bf(lrelu(x0.z)); v[3] = (short)f2bf(lrelu(x0.w));
            v[4] = (short)f2bf(lrelu(x1.x)); v[5] = (short)f2bf(lrelu(x1.y));
            v[6] = (short)f2bf(lrelu(x1.z)); v[7] = (short)f2bf(lrelu(x1.w));
        }
        *reinterpret_cast<short8*>(&lA[swz(r, c)]) = v;
    }
    __syncthreads();

    const int wid = tid >> 6, lane = tid & 63;
    const int wr = (wid >> 1) * 64, wc = (wid & 1) * 64;
    const int lrow = lane & 15, quad = lane >> 4;

    f32x4 acc[4][4];
    #pragma unroll
    for (int i = 0; i < 4; ++i)
        #pragma unroll
        for (int j = 0; j < 4; ++j)
            acc[i][j] = {0.f, 0.f, 0.f, 0.f};

    #pragma unroll
    for (int s = 0; s < 4; ++s) {
        const int kf = s * 32 + quad * 8;
        short8 a[4], b[4];
        #pragma unroll
        for (int i = 0; i < 4; ++i)
            a[i] = *reinterpret_cast<const short8*>(&lA[swz(wr + i * 16 + lrow, kf)]);
        #pragma unroll
        for (int j = 0; j < 4; ++j)
            b[j] = *reinterpret_cast<const short8*>(&lW[swz(wc + j * 16 + lrow, kf)]);
        #pragma unroll
        for (int i = 0; i < 4; ++i)
            #pragma unroll
            for (int j = 0; j < 4; ++j)
                acc[i][j] = __builtin_amdgcn_mfma_f32_16x16x32_bf16(a[i], b[j], acc[i][j], 0, 0, 0);
    }

    #pragma unroll
    for (int i = 0; i < 4; ++i) {
        #pragma unroll
        for (int reg = 0; reg < 4; ++reg) {
            int m = mbase + wr + i * 16 + quad * 4 + reg;
            if (m < N) {
                unsigned short* dst = c2 + (size_t)m * CDIM + wc + lrow;
                #pragma unroll
                for (int j = 0; j < 4; ++j)
                    dst[j * 16] = f2bf(lrelu(acc[i][j][reg]));
            }
        }
    }
}

__global__ void mask_mul_kernel(float* __restrict__ out,
                                const float* __restrict__ mask, int n4) {
    int i = blockIdx.x * blockDim.x + threadIdx.x;
    if (i >= n4) return;
    int row = i >> 5;
    float m = mask[row];
    float4 v = reinterpret_cast<float4*>(out)[i];
    v.x *= m; v.y *= m; v.z *= m; v.w *= m;
    reinterpret_cast<float4*>(out)[i] = v;
}

// ---------------------------------------------------------------- launch
extern "C" void kernel_launch(void* const* d_in, const int* in_sizes, int n_in,
                              void* d_out, int out_size, void* d_ws, size_t ws_size,
                              hipStream_t stream) {
    const float* feats   = (const float*)d_in[0];
    const float* W1      = (const float*)d_in[1];
    const float* W2      = (const float*)d_in[2];
    const float* W3      = (const float*)d_in[3];
    const int*   in_map  = (const int*)d_in[4];
    const int*   out_map = (const int*)d_in[5];
    const float* mask    = (const float*)d_in[6];
    float*       out     = (float*)d_out;

    const int N = in_sizes[0] / CDIM;        // 200000
    const int M = in_sizes[4] / KTAPS;       // 100000
    const size_t E = (size_t)KTAPS * M;

    auto al = [](size_t b) { return (b + 255) & ~(size_t)255; };
    size_t featsB = al((size_t)N * CDIM * 2);
    size_t c2B    = al((size_t)N * CDIM * 2);
    size_t w1B    = al((size_t)KTAPS * CDIM * CDIM * 2);
    size_t w2B    = al((size_t)CDIM * CDIM * 2);
    size_t recB   = al(E * 4);
    size_t base   = featsB + c2B + 2 * w1B + w2B + recB;

    int g = 0, ng = 0;
    for (int gg = KTAPS; gg >= 1; --gg) {
        int n_g = (KTAPS + gg - 1) / gg;
        size_t need = base + 2 * al(((size_t)N * n_g + 1) * 4) + al((size_t)gg * M * CDIM * 2);
        if (need <= ws_size) { g = gg; ng = n_g; break; }
    }

    char* p = (char*)d_ws;
    auto take = [&](size_t b) { char* r = p; p += al(b); return r; };
    unsigned short* feats_bf = (unsigned short*)take((size_t)N * CDIM * 2);
    unsigned short* c2_bf    = (unsigned short*)take((size_t)N * CDIM * 2);
    unsigned short* W1t      = (unsigned short*)take((size_t)KTAPS * CDIM * CDIM * 2);
    unsigned short* W3t      = (unsigned short*)take((size_t)KTAPS * CDIM * CDIM * 2);
    unsigned short* W2t      = (unsigned short*)take((size_t)CDIM * CDIM * 2);
    unsigned*       rec      = (unsigned*)take(E * 4);

    const int n4 = N * CDIM / 4;
    cvt_feats_kernel<<<(n4 + 255) / 256, 256, 0, stream>>>(feats, feats_bf, n4);
    const int wtot = 2 * KTAPS * CDIM * CDIM + CDIM * CDIM;
    cvt_weights_kernel<<<(wtot + 255) / 256, 256, 0, stream>>>(W1, W2, W3, W1t, W2t, W3t, g ? 1 : 0);

    const int MT = (M + 127) / 128;
    dim3 gm((M + 255) / 256, KTAPS);

    if (g) {
        int B = N * ng;
        int* bins   = (int*)take(((size_t)B + 1) * 4);
        int* starts = (int*)take(((size_t)B + 1) * 4);
        unsigned short* Ybuf = (unsigned short*)take((size_t)g * M * CDIM * 2);

        hipMemsetAsync(bins, 0, ((size_t)B + 1) * 4, stream);
        hist_kernel<<<gm, 256, 0, stream>>>(out_map, bins, M, ng, g);
        scan_kernel<<<1, 1024, 0, stream>>>(bins, starts, B);
        hipMemsetAsync(bins, 0, ((size_t)B + 1) * 4, stream);
        scatter_kernel<<<gm, 256, 0, stream>>>(out_map, starts, bins, rec, M, ng, g);

        const int rgrid = (N + 3) / 4;
        for (int grp = 0; grp < ng; ++grp) {
            int klo = grp * g;
            int kh  = klo + g; if (kh > KTAPS) kh = KTAPS;
            gemm_gather_kernel<<<dim3(MT, kh - klo), 256, 0, stream>>>(feats_bf, W1t, in_map, Ybuf, M, klo);
            reduce_kernel<<<rgrid, 256, 0, stream>>>(Ybuf, rec, starts, out, nullptr,
                                                     N, ng, grp, (unsigned)(klo * M), grp == 0, 0);
        }
        conv2_perm_kernel<<<(N + 127) / 128, 256, 0, stream>>>(out, W2t, c2_bf, N);
        for (int grp = 0; grp < ng; ++grp) {
            int klo = grp * g;
            int kh  = klo + g; if (kh > KTAPS) kh = KTAPS;
            gemm_gather_kernel<<<dim3(MT, kh - klo), 256, 0, stream>>>(c2_bf, W3t, in_map, Ybuf, M, klo);
            reduce_kernel<<<rgrid, 256, 0, stream>>>(Ybuf, rec, starts, out, mask,
                                                     N, ng, grp, (unsigned)(klo * M), grp == 0, grp == ng - 1);
        }
    } else {
        // atomic fallback (ws too small for materialization)
        hipMemsetAsync(out, 0, (size_t)N * CDIM * 4, stream);
        dim3 gs(MT, KTAPS);
        sconv_atomic_kernel<<<gs, 256, 0, stream>>>(feats_bf, W1t, in_map, out_map, out, M);
        conv2_true_kernel<<<(N + 127) / 128, 256, 0, stream>>>(out, W2t, c2_bf, N);
        hipMemsetAsync(out, 0, (size_t)N * CDIM * 4, stream);
        sconv_atomic_kernel<<<gs, 256, 0, stream>>>(c2_bf, W3t, in_map, out_map, out, M);
        mask_mul_kernel<<<(n4 + 255) / 256, 256, 0, stream>>>(out, mask, n4);
    }
}